// Round 1
// baseline (320.191 us; speedup 1.0000x reference)
//
#include <hip/hip_runtime.h>

#define S_LEN 1024
#define HD 64
#define NBH 64   // B*H = 4*16

typedef __attribute__((ext_vector_type(8))) short short8;            // 8 bf16
typedef __attribute__((ext_vector_type(4))) float floatx4;

// fp32 -> bf16 round-to-nearest-even
__device__ __forceinline__ unsigned short f2bf(float f) {
  unsigned int u = __builtin_bit_cast(unsigned int, f);
  u += 0x7fffu + ((u >> 16) & 1u);
  return (unsigned short)(u >> 16);
}

__device__ __forceinline__ short8 cvt8(floatx4 a0, floatx4 a1) {
  short8 f;
  f[0] = f2bf(a0[0]); f[1] = f2bf(a0[1]); f[2] = f2bf(a0[2]); f[3] = f2bf(a0[3]);
  f[4] = f2bf(a1[0]); f[5] = f2bf(a1[1]); f[6] = f2bf(a1[2]); f[7] = f2bf(a1[3]);
  return f;
}

// ---------------------------------------------------------------------------
// Kernel 1 (unchanged): MT[h][n][k] = bf16( 32*(n==k) + Wd[h]*W[h][k][n] )
// ---------------------------------------------------------------------------
__global__ __launch_bounds__(256) void prep_small_kernel(
    const float* __restrict__ W, const float* __restrict__ Wd,
    unsigned short* __restrict__ MT) {
  int idx = blockIdx.x * 256 + threadIdx.x;  // h*4096 + n*64 + k
  int h  = idx >> 12;
  int n  = (idx >> 6) & 63;
  int kk = idx & 63;
  float v = Wd[h] * W[(h << 12) + (kk << 6) + n];
  if (kk == n) v += 32.0f;
  MT[idx] = f2bf(v);
}

// ---------------------------------------------------------------------------
// Kernel 2 (fused): per 128x128 out tile —
//   stage A: convert this block's 128 k-rows fp32->bf16 into klds
//   stage B: q' = bf16(q) @ M_h (MFMA) for this block's 128 q-rows into qlds
//   stage C: 128x128 d-tile = q' @ k'^T (+ Wd*b folded into C), LDS-transpose
//            epilogue, PLAIN (non-NT) dwordx4 stores — the fill path proves
//            plain stores sustain 81% of peak; NT is the A/B under test.
// LDS rows padded to 144 B (QROW=72 shorts): keeps b128 frag reads 16B-aligned
// and turns the 128B-stride 16-way bank conflict into a free 2-way alias.
// ---------------------------------------------------------------------------
#define QROW 72   // shorts per LDS row (144 B)
#define LPAD 68   // epilogue floats per row (unchanged, proven free)

__global__ __launch_bounds__(256) void fused_kernel(
    const float* __restrict__ q, const float* __restrict__ k,
    const unsigned short* __restrict__ MT,
    const float* __restrict__ b, const float* __restrict__ Wd,
    float* __restrict__ out) {
  // 2 * 128 * 72 shorts = 36864 B; epilogue reuses the same region (34816 B)
  __shared__ __align__(16) unsigned short smem[2 * 128 * QROW];
  unsigned short* __restrict__ qlds = smem;
  unsigned short* __restrict__ klds = smem + 128 * QROW;

  const int bh   = blockIdx.z;
  const int h    = bh & 15;
  const int wave = threadIdx.x >> 6;
  const int lane = threadIdx.x & 63;
  const int l15  = lane & 15;
  const int quad = lane >> 4;

  const float* __restrict__ qg = q + ((size_t)bh << 16);
  const float* __restrict__ kg = k + ((size_t)bh << 16);
  const unsigned short* __restrict__ mt = MT + (h << 12);

  // ---- stage A: k' rows [wave*32, wave*32+32) -> klds (bf16)
  {
    const int rbase = wave * 32 + (lane >> 3);   // + it*8
    const int col   = (lane & 7) * 8;
#pragma unroll
    for (int it = 0; it < 4; ++it) {
      int rl = rbase + it * 8;
      const float* src = kg + (size_t)(blockIdx.x * 128 + rl) * HD + col;
      floatx4 a0 = *(const floatx4*)src;
      floatx4 a1 = *(const floatx4*)(src + 4);
      *(short8*)(klds + rl * QROW + col) = cvt8(a0, a1);
    }
  }

  // ---- stage B: q' rows [wave*32, wave*32+32) = bf16(q) @ M_h -> qlds
  {
    short8 bm[4][2];
#pragma unroll
    for (int nt = 0; nt < 4; nt++)
#pragma unroll
      for (int ks = 0; ks < 2; ks++)
        bm[nt][ks] = *(const short8*)(mt + (nt * 16 + l15) * HD + ks * 32 + quad * 8);

    short8 aq[2][2];
#pragma unroll
    for (int m = 0; m < 2; m++)
#pragma unroll
      for (int ks = 0; ks < 2; ks++) {
        const float* src = qg + (size_t)(blockIdx.y * 128 + wave * 32 + m * 16 + l15) * HD
                              + ks * 32 + quad * 8;
        aq[m][ks] = cvt8(*(const floatx4*)src, *(const floatx4*)(src + 4));
      }

    floatx4 accq[2][4];
#pragma unroll
    for (int m = 0; m < 2; m++)
#pragma unroll
      for (int nt = 0; nt < 4; nt++) {
        accq[m][nt] = (floatx4){0.f, 0.f, 0.f, 0.f};
#pragma unroll
        for (int ks = 0; ks < 2; ks++)
          accq[m][nt] = __builtin_amdgcn_mfma_f32_16x16x32_bf16(
              aq[m][ks], bm[nt][ks], accq[m][nt], 0, 0, 0);
      }
    // acc layout: col = l15, row = quad*4 + r  (proven in prep_q)
#pragma unroll
    for (int m = 0; m < 2; m++)
#pragma unroll
      for (int nt = 0; nt < 4; nt++)
#pragma unroll
        for (int r = 0; r < 4; r++)
          qlds[(wave * 32 + m * 16 + quad * 4 + r) * QROW + nt * 16 + l15] =
              f2bf(accq[m][nt][r]);
  }
  __syncthreads();

  // ---- stage C: frag loads from LDS (2-way bank alias only, free)
  const int wr0 = (wave >> 1) * 64;
  const int wc0 = (wave & 1) * 64;
  short8 afrag[4][2], bfrag[4][2];
#pragma unroll
  for (int t = 0; t < 4; t++)
#pragma unroll
    for (int ks = 0; ks < 2; ks++) {
      afrag[t][ks] = *(const short8*)(qlds + (wr0 + t * 16 + l15) * QROW + ks * 32 + quad * 8);
      bfrag[t][ks] = *(const short8*)(klds + (wc0 + t * 16 + l15) * QROW + ks * 32 + quad * 8);
    }
  __syncthreads();  // frags in regs; LDS region is now reusable by the epilogue

  const float cbias = Wd[h] * b[h];
  floatx4 acc[4][4];
#pragma unroll
  for (int mtile = 0; mtile < 4; mtile++)
#pragma unroll
    for (int nt = 0; nt < 4; nt++) {
      acc[mtile][nt] = (floatx4){cbias, cbias, cbias, cbias};
#pragma unroll
      for (int ks = 0; ks < 2; ks++)
        acc[mtile][nt] = __builtin_amdgcn_mfma_f32_16x16x32_bf16(
            afrag[mtile][ks], bfrag[nt][ks], acc[mtile][nt], 0, 0, 0);
    }

  // Epilogue: per-wave private LDS region, 2 chunks of 32 rows. No barriers —
  // within-wave LDS ordering via explicit lgkmcnt(0). PLAIN dwordx4 stores.
  const int row0 = blockIdx.y * 128 + wr0;
  const int col0 = blockIdx.x * 128 + wc0;
  float* __restrict__ elds = (float*)(void*)smem;
  float* __restrict__ wlds = elds + wave * (32 * LPAD);
  float* __restrict__ ob = out + ((size_t)bh << 20);
#pragma unroll
  for (int c = 0; c < 2; ++c) {
#pragma unroll
    for (int mr = 0; mr < 2; ++mr) {
      int mtile = 2 * c + mr;
#pragma unroll
      for (int nt = 0; nt < 4; nt++)
#pragma unroll
        for (int r = 0; r < 4; r++)
          wlds[(mr * 16 + quad * 4 + r) * LPAD + nt * 16 + l15] = acc[mtile][nt][r];
    }
    __asm__ volatile("s_waitcnt lgkmcnt(0)" ::: "memory");
#pragma unroll
    for (int g = 0; g < 8; ++g) {
      int row = g * 4 + quad;
      floatx4 v = *(const floatx4*)(wlds + row * LPAD + l15 * 4);
      *(floatx4*)(ob + (size_t)(row0 + c * 32 + row) * S_LEN + col0 + l15 * 4) = v;
    }
    __asm__ volatile("s_waitcnt lgkmcnt(0)" ::: "memory");
  }
}

extern "C" void kernel_launch(void* const* d_in, const int* in_sizes, int n_in,
                              void* d_out, int out_size, void* d_ws, size_t ws_size,
                              hipStream_t stream) {
  const float* q  = (const float*)d_in[0];
  const float* k  = (const float*)d_in[1];
  const float* W  = (const float*)d_in[2];
  const float* b  = (const float*)d_in[3];
  const float* Wd = (const float*)d_in[4];
  float* out = (float*)d_out;

  unsigned short* MT = (unsigned short*)d_ws;  // 128 KB

  prep_small_kernel<<<256, 256, 0, stream>>>(W, Wd, MT);
  fused_kernel<<<dim3(8, 8, NBH), 256, 0, stream>>>(q, k, MT, b, Wd, out);
}

// Round 2
// 318.959 us; speedup vs baseline: 1.0039x; 1.0039x over previous
//
#include <hip/hip_runtime.h>

#define S_LEN 1024
#define HD 64
#define NBH 64   // B*H = 4*16

typedef __attribute__((ext_vector_type(8))) short short8;            // 8 bf16
typedef __attribute__((ext_vector_type(4))) float floatx4;

// fp32 -> bf16 round-to-nearest-even
__device__ __forceinline__ unsigned short f2bf(float f) {
  unsigned int u = __builtin_bit_cast(unsigned int, f);
  u += 0x7fffu + ((u >> 16) & 1u);
  return (unsigned short)(u >> 16);
}

__device__ __forceinline__ short8 cvt8(floatx4 a0, floatx4 a1) {
  short8 f;
  f[0] = f2bf(a0[0]); f[1] = f2bf(a0[1]); f[2] = f2bf(a0[2]); f[3] = f2bf(a0[3]);
  f[4] = f2bf(a1[0]); f[5] = f2bf(a1[1]); f[6] = f2bf(a1[2]); f[7] = f2bf(a1[3]);
  return f;
}

// ---------------------------------------------------------------------------
// Kernel 1 (unchanged): MT[h][n][k] = bf16( 32*(n==k) + Wd[h]*W[h][k][n] )
// ---------------------------------------------------------------------------
__global__ __launch_bounds__(256) void prep_small_kernel(
    const float* __restrict__ W, const float* __restrict__ Wd,
    unsigned short* __restrict__ MT) {
  int idx = blockIdx.x * 256 + threadIdx.x;  // h*4096 + n*64 + k
  int h  = idx >> 12;
  int n  = (idx >> 6) & 63;
  int kk = idx & 63;
  float v = Wd[h] * W[(h << 12) + (kk << 6) + n];
  if (kk == n) v += 32.0f;
  MT[idx] = f2bf(v);
}

// ---------------------------------------------------------------------------
// Kernel 2 (fused, R1 structure) — SINGLE CHANGE vs R1: epilogue stores are
// __builtin_nontemporal_store again (completes the NT-vs-plain / fused-vs-not
// A/B matrix; R0=NT+unfused=306, R1=plain+fused=320).
// ---------------------------------------------------------------------------
#define QROW 72   // shorts per LDS row (144 B)
#define LPAD 68   // epilogue floats per row (unchanged, proven free)

__global__ __launch_bounds__(256) void fused_kernel(
    const float* __restrict__ q, const float* __restrict__ k,
    const unsigned short* __restrict__ MT,
    const float* __restrict__ b, const float* __restrict__ Wd,
    float* __restrict__ out) {
  // 2 * 128 * 72 shorts = 36864 B; epilogue reuses the same region (34816 B)
  __shared__ __align__(16) unsigned short smem[2 * 128 * QROW];
  unsigned short* __restrict__ qlds = smem;
  unsigned short* __restrict__ klds = smem + 128 * QROW;

  const int bh   = blockIdx.z;
  const int h    = bh & 15;
  const int wave = threadIdx.x >> 6;
  const int lane = threadIdx.x & 63;
  const int l15  = lane & 15;
  const int quad = lane >> 4;

  const float* __restrict__ qg = q + ((size_t)bh << 16);
  const float* __restrict__ kg = k + ((size_t)bh << 16);
  const unsigned short* __restrict__ mt = MT + (h << 12);

  // ---- stage A: k' rows [wave*32, wave*32+32) -> klds (bf16)
  {
    const int rbase = wave * 32 + (lane >> 3);   // + it*8
    const int col   = (lane & 7) * 8;
#pragma unroll
    for (int it = 0; it < 4; ++it) {
      int rl = rbase + it * 8;
      const float* src = kg + (size_t)(blockIdx.x * 128 + rl) * HD + col;
      floatx4 a0 = *(const floatx4*)src;
      floatx4 a1 = *(const floatx4*)(src + 4);
      *(short8*)(klds + rl * QROW + col) = cvt8(a0, a1);
    }
  }

  // ---- stage B: q' rows [wave*32, wave*32+32) = bf16(q) @ M_h -> qlds
  {
    short8 bm[4][2];
#pragma unroll
    for (int nt = 0; nt < 4; nt++)
#pragma unroll
      for (int ks = 0; ks < 2; ks++)
        bm[nt][ks] = *(const short8*)(mt + (nt * 16 + l15) * HD + ks * 32 + quad * 8);

    short8 aq[2][2];
#pragma unroll
    for (int m = 0; m < 2; m++)
#pragma unroll
      for (int ks = 0; ks < 2; ks++) {
        const float* src = qg + (size_t)(blockIdx.y * 128 + wave * 32 + m * 16 + l15) * HD
                              + ks * 32 + quad * 8;
        aq[m][ks] = cvt8(*(const floatx4*)src, *(const floatx4*)(src + 4));
      }

    floatx4 accq[2][4];
#pragma unroll
    for (int m = 0; m < 2; m++)
#pragma unroll
      for (int nt = 0; nt < 4; nt++) {
        accq[m][nt] = (floatx4){0.f, 0.f, 0.f, 0.f};
#pragma unroll
        for (int ks = 0; ks < 2; ks++)
          accq[m][nt] = __builtin_amdgcn_mfma_f32_16x16x32_bf16(
              aq[m][ks], bm[nt][ks], accq[m][nt], 0, 0, 0);
      }
    // acc layout: col = l15, row = quad*4 + r  (proven in prep_q)
#pragma unroll
    for (int m = 0; m < 2; m++)
#pragma unroll
      for (int nt = 0; nt < 4; nt++)
#pragma unroll
        for (int r = 0; r < 4; r++)
          qlds[(wave * 32 + m * 16 + quad * 4 + r) * QROW + nt * 16 + l15] =
              f2bf(accq[m][nt][r]);
  }
  __syncthreads();

  // ---- stage C: frag loads from LDS (2-way bank alias only, free)
  const int wr0 = (wave >> 1) * 64;
  const int wc0 = (wave & 1) * 64;
  short8 afrag[4][2], bfrag[4][2];
#pragma unroll
  for (int t = 0; t < 4; t++)
#pragma unroll
    for (int ks = 0; ks < 2; ks++) {
      afrag[t][ks] = *(const short8*)(qlds + (wr0 + t * 16 + l15) * QROW + ks * 32 + quad * 8);
      bfrag[t][ks] = *(const short8*)(klds + (wc0 + t * 16 + l15) * QROW + ks * 32 + quad * 8);
    }
  __syncthreads();  // frags in regs; LDS region is now reusable by the epilogue

  const float cbias = Wd[h] * b[h];
  floatx4 acc[4][4];
#pragma unroll
  for (int mtile = 0; mtile < 4; mtile++)
#pragma unroll
    for (int nt = 0; nt < 4; nt++) {
      acc[mtile][nt] = (floatx4){cbias, cbias, cbias, cbias};
#pragma unroll
      for (int ks = 0; ks < 2; ks++)
        acc[mtile][nt] = __builtin_amdgcn_mfma_f32_16x16x32_bf16(
            afrag[mtile][ks], bfrag[nt][ks], acc[mtile][nt], 0, 0, 0);
    }

  // Epilogue: per-wave private LDS region, 2 chunks of 32 rows. No barriers —
  // within-wave LDS ordering via explicit lgkmcnt(0). NT dwordx4 stores.
  const int row0 = blockIdx.y * 128 + wr0;
  const int col0 = blockIdx.x * 128 + wc0;
  float* __restrict__ elds = (float*)(void*)smem;
  float* __restrict__ wlds = elds + wave * (32 * LPAD);
  float* __restrict__ ob = out + ((size_t)bh << 20);
#pragma unroll
  for (int c = 0; c < 2; ++c) {
#pragma unroll
    for (int mr = 0; mr < 2; ++mr) {
      int mtile = 2 * c + mr;
#pragma unroll
      for (int nt = 0; nt < 4; nt++)
#pragma unroll
        for (int r = 0; r < 4; r++)
          wlds[(mr * 16 + quad * 4 + r) * LPAD + nt * 16 + l15] = acc[mtile][nt][r];
    }
    __asm__ volatile("s_waitcnt lgkmcnt(0)" ::: "memory");
#pragma unroll
    for (int g = 0; g < 8; ++g) {
      int row = g * 4 + quad;
      floatx4 v = *(const floatx4*)(wlds + row * LPAD + l15 * 4);
      __builtin_nontemporal_store(
          v, (floatx4*)(ob + (size_t)(row0 + c * 32 + row) * S_LEN + col0 + l15 * 4));
    }
    __asm__ volatile("s_waitcnt lgkmcnt(0)" ::: "memory");
  }
}

extern "C" void kernel_launch(void* const* d_in, const int* in_sizes, int n_in,
                              void* d_out, int out_size, void* d_ws, size_t ws_size,
                              hipStream_t stream) {
  const float* q  = (const float*)d_in[0];
  const float* k  = (const float*)d_in[1];
  const float* W  = (const float*)d_in[2];
  const float* b  = (const float*)d_in[3];
  const float* Wd = (const float*)d_in[4];
  float* out = (float*)d_out;

  unsigned short* MT = (unsigned short*)d_ws;  // 128 KB

  prep_small_kernel<<<256, 256, 0, stream>>>(W, Wd, MT);
  fused_kernel<<<dim3(8, 8, NBH), 256, 0, stream>>>(q, k, MT, b, Wd, out);
}

// Round 3
// 310.930 us; speedup vs baseline: 1.0298x; 1.0258x over previous
//
#include <hip/hip_runtime.h>

#define S_LEN 1024
#define HD 64
#define NBH 64   // B*H = 4*16

typedef __attribute__((ext_vector_type(8))) short short8;            // 8 bf16
typedef __attribute__((ext_vector_type(4))) float floatx4;
typedef __attribute__((ext_vector_type(4))) unsigned short ushort4v; // 4 bf16

// fp32 -> bf16 round-to-nearest-even
__device__ __forceinline__ unsigned short f2bf(float f) {
  unsigned int u = __builtin_bit_cast(unsigned int, f);
  u += 0x7fffu + ((u >> 16) & 1u);
  return (unsigned short)(u >> 16);
}

// ---------------------------------------------------------------------------
// Kernel 1: MT[h][n][k] = bf16( 32*(n==k) + Wd[h]*W[h][k][n] )   (65536 elems)
// ---------------------------------------------------------------------------
__global__ __launch_bounds__(256) void prep_small_kernel(
    const float* __restrict__ W, const float* __restrict__ Wd,
    unsigned short* __restrict__ MT) {
  int idx = blockIdx.x * 256 + threadIdx.x;  // h*4096 + n*64 + k
  int h  = idx >> 12;
  int n  = (idx >> 6) & 63;
  int kk = idx & 63;
  float v = Wd[h] * W[(h << 12) + (kk << 6) + n];
  if (kk == n) v += 32.0f;
  MT[idx] = f2bf(v);
}

// ---------------------------------------------------------------------------
// Kernel 2: k' = bf16(k), elementwise. 4M elems, 4 per thread.
// ---------------------------------------------------------------------------
__global__ __launch_bounds__(256) void convert_k_kernel(
    const float* __restrict__ k, unsigned short* __restrict__ kp) {
  size_t t = (size_t)blockIdx.x * 256 + threadIdx.x;  // 0..1M-1
  floatx4 v = *(const floatx4*)(k + t * 4);
  ushort4v o;
  o[0] = f2bf(v[0]); o[1] = f2bf(v[1]); o[2] = f2bf(v[2]); o[3] = f2bf(v[3]);
  *(ushort4v*)(kp + t * 4) = o;
}

// ---------------------------------------------------------------------------
// Kernel 3: q'[bh] = bf16( q[bh] @ M_h ).  Grid (16, 64); wave does 16 rows.
// ---------------------------------------------------------------------------
__global__ __launch_bounds__(256) void prep_q_kernel(
    const float* __restrict__ q, const unsigned short* __restrict__ MT,
    unsigned short* __restrict__ qp) {
  const int bh   = blockIdx.y;
  const int h    = bh & 15;
  const int wave = threadIdx.x >> 6;
  const int lane = threadIdx.x & 63;
  const int l15  = lane & 15;
  const int quad = lane >> 4;
  const int i0   = blockIdx.x * 64 + wave * 16;

  const float* __restrict__ qb = q + (size_t)bh * S_LEN * HD;
  const unsigned short* __restrict__ mt = MT + (h << 12);

  short8 bfrag[4][2];
#pragma unroll
  for (int nt = 0; nt < 4; nt++)
#pragma unroll
    for (int ks = 0; ks < 2; ks++)
      bfrag[nt][ks] = *(const short8*)(mt + (nt * 16 + l15) * HD + ks * 32 + quad * 8);

  short8 afrag[2];
#pragma unroll
  for (int ks = 0; ks < 2; ks++) {
    const float* src = qb + (size_t)(i0 + l15) * HD + ks * 32 + quad * 8;
    floatx4 a0 = *(const floatx4*)src;
    floatx4 a1 = *(const floatx4*)(src + 4);
    short8 f;
    f[0] = f2bf(a0[0]); f[1] = f2bf(a0[1]); f[2] = f2bf(a0[2]); f[3] = f2bf(a0[3]);
    f[4] = f2bf(a1[0]); f[5] = f2bf(a1[1]); f[6] = f2bf(a1[2]); f[7] = f2bf(a1[3]);
    afrag[ks] = f;
  }

  floatx4 acc[4];
#pragma unroll
  for (int nt = 0; nt < 4; nt++) {
    acc[nt] = (floatx4){0.f, 0.f, 0.f, 0.f};
#pragma unroll
    for (int ks = 0; ks < 2; ks++)
      acc[nt] = __builtin_amdgcn_mfma_f32_16x16x32_bf16(afrag[ks], bfrag[nt][ks],
                                                        acc[nt], 0, 0, 0);
  }

  unsigned short* __restrict__ qpb = qp + (size_t)bh * S_LEN * HD;
#pragma unroll
  for (int nt = 0; nt < 4; nt++)
#pragma unroll
    for (int r = 0; r < 4; r++)
      qpb[(i0 + quad * 4 + r) * HD + nt * 16 + l15] = f2bf(acc[nt][r]);
}

// ---------------------------------------------------------------------------
// Kernel 4 (CHANGED): pipelined multi-tile main kernel.
// Grid (8, 2, 64) = 1024 blocks. Each block: fixed 128-row stripe, loops over
// 4 col-tiles of 128. q-frags loaded ONCE (amortized 4x). Per tile:
//   prefetch next tile's k-frags  ->  MFMA (waits only on older loads,
//   never on stores)  ->  LDS-transpose epilogue + 16 NT dwordx4 stores.
// Stores of tile c drain under MFMA/LDS of tile c+1: continuous store stream
// instead of one end-of-block burst (Little's-law fix for the 2.3 TB/s wall).
// bfrag double-buffered [2], all indices compile-time via full unroll.
// ---------------------------------------------------------------------------
#define LPAD 68  // 68%32=4 -> write-phase 2-way bank alias (free); 16B-aligned rows
__global__ __launch_bounds__(256) void main_kernel(
    const unsigned short* __restrict__ qp, const unsigned short* __restrict__ kp,
    const float* __restrict__ b, const float* __restrict__ Wd,
    float* __restrict__ out) {
  __shared__ __align__(16) float lds[4 * 32 * LPAD];  // 34816 B, per-wave private

  const int bh   = blockIdx.z;
  const int h    = bh & 15;
  const int wave = threadIdx.x >> 6;
  const int lane = threadIdx.x & 63;
  const int l15  = lane & 15;
  const int quad = lane >> 4;
  const int row0 = blockIdx.x * 128 + (wave >> 1) * 64;
  const int colw = (wave & 1) * 64;
  const int colbase = blockIdx.y * 512;  // 4 tiles of 128 cols

  const unsigned short* __restrict__ qb = qp + ((size_t)bh << 16);
  const unsigned short* __restrict__ kb = kp + ((size_t)bh << 16);

  // A-fragments: load once, reuse for all 4 col-tiles.
  short8 afrag[4][2];
#pragma unroll
  for (int t = 0; t < 4; t++)
#pragma unroll
    for (int ks = 0; ks < 2; ks++)
      afrag[t][ks] = *(const short8*)(qb + (row0 + t * 16 + l15) * HD + ks * 32 + quad * 8);

  const float cbias = Wd[h] * b[h];
  float* __restrict__ wlds = lds + wave * (32 * LPAD);
  float* __restrict__ ob = out + ((size_t)bh << 20);

  // B-fragment double buffer; preload tile 0.
  short8 bfrag[2][4][2];
#pragma unroll
  for (int t = 0; t < 4; t++)
#pragma unroll
    for (int ks = 0; ks < 2; ks++)
      bfrag[0][t][ks] =
          *(const short8*)(kb + (colbase + colw + t * 16 + l15) * HD + ks * 32 + quad * 8);

#pragma unroll
  for (int c = 0; c < 4; ++c) {
    // ---- prefetch tile c+1 B-frags (issued before MFMA and before the store
    // burst, so nothing downstream ever vmcnt-waits on stores)
    if (c < 3) {
      const int coln = colbase + (c + 1) * 128 + colw;
#pragma unroll
      for (int t = 0; t < 4; t++)
#pragma unroll
        for (int ks = 0; ks < 2; ks++)
          bfrag[(c + 1) & 1][t][ks] =
              *(const short8*)(kb + (coln + t * 16 + l15) * HD + ks * 32 + quad * 8);
    }

    // ---- MFMA tile c
    floatx4 acc[4][4];
#pragma unroll
    for (int mt = 0; mt < 4; mt++)
#pragma unroll
      for (int nt = 0; nt < 4; nt++) {
        acc[mt][nt] = (floatx4){cbias, cbias, cbias, cbias};  // bias folded into C
#pragma unroll
        for (int ks = 0; ks < 2; ks++)
          acc[mt][nt] = __builtin_amdgcn_mfma_f32_16x16x32_bf16(
              afrag[mt][ks], bfrag[c & 1][nt][ks], acc[mt][nt], 0, 0, 0);
      }

    // ---- epilogue tile c: per-wave private LDS transpose, 2 chunks of 32 rows.
    // No barriers — within-wave LDS ordering via explicit lgkmcnt(0).
    const int col0 = colbase + c * 128 + colw;
#pragma unroll
    for (int ch = 0; ch < 2; ++ch) {
#pragma unroll
      for (int mr = 0; mr < 2; ++mr) {
        int mtile = 2 * ch + mr;
#pragma unroll
        for (int nt = 0; nt < 4; nt++)
#pragma unroll
          for (int r = 0; r < 4; r++)
            wlds[(mr * 16 + quad * 4 + r) * LPAD + nt * 16 + l15] = acc[mtile][nt][r];
      }
      __asm__ volatile("s_waitcnt lgkmcnt(0)" ::: "memory");
#pragma unroll
      for (int g = 0; g < 8; ++g) {
        int row = g * 4 + quad;
        floatx4 v = *(const floatx4*)(wlds + row * LPAD + l15 * 4);
        __builtin_nontemporal_store(
            v, (floatx4*)(ob + (size_t)(row0 + ch * 32 + row) * S_LEN + col0 + l15 * 4));
      }
      __asm__ volatile("s_waitcnt lgkmcnt(0)" ::: "memory");
    }
  }
}

extern "C" void kernel_launch(void* const* d_in, const int* in_sizes, int n_in,
                              void* d_out, int out_size, void* d_ws, size_t ws_size,
                              hipStream_t stream) {
  const float* q  = (const float*)d_in[0];
  const float* k  = (const float*)d_in[1];
  const float* W  = (const float*)d_in[2];
  const float* b  = (const float*)d_in[3];
  const float* Wd = (const float*)d_in[4];
  float* out = (float*)d_out;

  unsigned short* qp = (unsigned short*)d_ws;                 // 8 MB
  unsigned short* kp = qp + (size_t)NBH * S_LEN * HD;         // 8 MB
  unsigned short* MT = kp + (size_t)NBH * S_LEN * HD;         // 128 KB

  prep_small_kernel<<<256, 256, 0, stream>>>(W, Wd, MT);
  convert_k_kernel<<<4096, 256, 0, stream>>>(k, kp);
  prep_q_kernel<<<dim3(16, NBH), 256, 0, stream>>>(q, MT, qp);
  main_kernel<<<dim3(8, 2, NBH), 256, 0, stream>>>(qp, kp, b, Wd, out);
}

// Round 4
// 306.722 us; speedup vs baseline: 1.0439x; 1.0137x over previous
//
#include <hip/hip_runtime.h>

#define S_LEN 1024
#define HD 64
#define NBH 64   // B*H = 4*16

typedef __attribute__((ext_vector_type(8))) short short8;            // 8 bf16
typedef __attribute__((ext_vector_type(4))) float floatx4;
typedef __attribute__((ext_vector_type(4))) unsigned short ushort4v; // 4 bf16

// fp32 -> bf16 round-to-nearest-even
__device__ __forceinline__ unsigned short f2bf(float f) {
  unsigned int u = __builtin_bit_cast(unsigned int, f);
  u += 0x7fffu + ((u >> 16) & 1u);
  return (unsigned short)(u >> 16);
}

// ---------------------------------------------------------------------------
// Kernel 1 (MERGED preps): one dispatch, 5120 blocks.
//   blocks [0, 4096):  k' = bf16(k) elementwise (4 elems/thread) -> kp
//   blocks [4096,5120): q' = bf16( q @ M_h ) -> qp, where the block computes
//                       its head's M tile (64x64) from W/Wd directly into LDS
//                       (no MT global round-trip, no prep_small kernel, no
//                       inter-kernel dependency). Numerics bit-identical to
//                       the old prep_small+prep_q chain: same f2bf rounding,
//                       same MFMA operands and accumulation order.
// MROW=72 pad: frag ds_read_b128 at 144 B row stride = free 2-way bank alias.
// ---------------------------------------------------------------------------
#define MROW 72
__global__ __launch_bounds__(256) void prep_all_kernel(
    const float* __restrict__ k, const float* __restrict__ q,
    const float* __restrict__ W, const float* __restrict__ Wd,
    unsigned short* __restrict__ kp, unsigned short* __restrict__ qp) {
  __shared__ __align__(16) unsigned short mtlds[64 * MROW];  // 9216 B

  const int bid = blockIdx.x;
  const int tid = threadIdx.x;

  if (bid < 4096) {
    // ---- convert_k part (identical to old convert_k_kernel)
    size_t t = (size_t)bid * 256 + tid;  // 0..1M-1
    floatx4 v = *(const floatx4*)(k + t * 4);
    ushort4v o;
    o[0] = f2bf(v[0]); o[1] = f2bf(v[1]); o[2] = f2bf(v[2]); o[3] = f2bf(v[3]);
    *(ushort4v*)(kp + t * 4) = o;
    return;
  }

  // ---- prep_q part
  const int pb   = bid - 4096;     // 0..1023
  const int bh   = pb >> 4;        // 0..63
  const int xb   = pb & 15;        // 0..15
  const int h    = bh & 15;
  const int wave = tid >> 6;
  const int lane = tid & 63;
  const int l15  = lane & 15;
  const int quad = lane >> 4;
  const int i0   = xb * 64 + wave * 16;

  // Build M_h tile in LDS: M[n][kk] = bf16( Wd[h]*W[h][kk][n] + 32*(n==kk) ).
  // Thread: row n = tid>>2, cols kk0..kk0+15 (kk0 = (tid&3)*16).
  {
    const float wd = Wd[h];
    const int n   = tid >> 2;
    const int kk0 = (tid & 3) * 16;
    const float* __restrict__ wh = W + (h << 12);
    short8 f0, f1;
#pragma unroll
    for (int j = 0; j < 8; j++) {
      int kk = kk0 + j;
      float v = wd * wh[(kk << 6) + n];
      if (kk == n) v += 32.0f;
      f0[j] = f2bf(v);
    }
#pragma unroll
    for (int j = 0; j < 8; j++) {
      int kk = kk0 + 8 + j;
      float v = wd * wh[(kk << 6) + n];
      if (kk == n) v += 32.0f;
      f1[j] = f2bf(v);
    }
    *(short8*)(mtlds + n * MROW + kk0)     = f0;
    *(short8*)(mtlds + n * MROW + kk0 + 8) = f1;
  }
  __syncthreads();

  const float* __restrict__ qb = q + (size_t)bh * S_LEN * HD;

  short8 bfrag[4][2];
#pragma unroll
  for (int nt = 0; nt < 4; nt++)
#pragma unroll
    for (int ks = 0; ks < 2; ks++)
      bfrag[nt][ks] = *(const short8*)(mtlds + (nt * 16 + l15) * MROW + ks * 32 + quad * 8);

  short8 afrag[2];
#pragma unroll
  for (int ks = 0; ks < 2; ks++) {
    const float* src = qb + (size_t)(i0 + l15) * HD + ks * 32 + quad * 8;
    floatx4 a0 = *(const floatx4*)src;
    floatx4 a1 = *(const floatx4*)(src + 4);
    short8 f;
    f[0] = f2bf(a0[0]); f[1] = f2bf(a0[1]); f[2] = f2bf(a0[2]); f[3] = f2bf(a0[3]);
    f[4] = f2bf(a1[0]); f[5] = f2bf(a1[1]); f[6] = f2bf(a1[2]); f[7] = f2bf(a1[3]);
    afrag[ks] = f;
  }

  floatx4 acc[4];
#pragma unroll
  for (int nt = 0; nt < 4; nt++) {
    acc[nt] = (floatx4){0.f, 0.f, 0.f, 0.f};
#pragma unroll
    for (int ks = 0; ks < 2; ks++)
      acc[nt] = __builtin_amdgcn_mfma_f32_16x16x32_bf16(afrag[ks], bfrag[nt][ks],
                                                        acc[nt], 0, 0, 0);
  }

  unsigned short* __restrict__ qpb = qp + (size_t)bh * S_LEN * HD;
#pragma unroll
  for (int nt = 0; nt < 4; nt++)
#pragma unroll
    for (int r = 0; r < 4; r++)
      qpb[(i0 + quad * 4 + r) * HD + nt * 16 + l15] = f2bf(acc[nt][r]);
}

// ---------------------------------------------------------------------------
// Kernel 2: d[bh] = q' @ k'^T + Wd_h*b_h.  EXACT R0 main kernel (best: 306.3).
// Grid (8, 8, 64); 4 waves (2x2), each 64x64. Epilogue: LDS transpose so
// stores are global_store_dwordx4 (wave covers 4 x 256 B contiguous).
// ---------------------------------------------------------------------------
#define LPAD 68  // 68%32=4 -> write-phase 2-way bank alias (free); 16B-aligned rows
__global__ __launch_bounds__(256) void main_kernel(
    const unsigned short* __restrict__ qp, const unsigned short* __restrict__ kp,
    const float* __restrict__ b, const float* __restrict__ Wd,
    float* __restrict__ out) {
  __shared__ __align__(16) float lds[4 * 32 * LPAD];  // 34816 B

  const int bh   = blockIdx.z;
  const int h    = bh & 15;
  const int wave = threadIdx.x >> 6;
  const int lane = threadIdx.x & 63;
  const int l15  = lane & 15;
  const int quad = lane >> 4;
  const int row0 = blockIdx.y * 128 + (wave >> 1) * 64;
  const int col0 = blockIdx.x * 128 + (wave & 1) * 64;

  const unsigned short* __restrict__ qb = qp + ((size_t)bh << 16);
  const unsigned short* __restrict__ kb = kp + ((size_t)bh << 16);

  short8 afrag[4][2], bfrag[4][2];
#pragma unroll
  for (int t = 0; t < 4; t++)
#pragma unroll
    for (int ks = 0; ks < 2; ks++) {
      afrag[t][ks] = *(const short8*)(qb + (row0 + t * 16 + l15) * HD + ks * 32 + quad * 8);
      bfrag[t][ks] = *(const short8*)(kb + (col0 + t * 16 + l15) * HD + ks * 32 + quad * 8);
    }

  const float cbias = Wd[h] * b[h];
  floatx4 acc[4][4];
#pragma unroll
  for (int mtile = 0; mtile < 4; mtile++)
#pragma unroll
    for (int nt = 0; nt < 4; nt++) {
      acc[mtile][nt] = (floatx4){cbias, cbias, cbias, cbias};  // bias folded into C
#pragma unroll
      for (int ks = 0; ks < 2; ks++)
        acc[mtile][nt] = __builtin_amdgcn_mfma_f32_16x16x32_bf16(
            afrag[mtile][ks], bfrag[nt][ks], acc[mtile][nt], 0, 0, 0);
    }

  // Epilogue: per-wave private LDS region, 2 chunks of 32 rows. No barriers —
  // within-wave LDS ordering via explicit lgkmcnt(0).
  float* __restrict__ wlds = lds + wave * (32 * LPAD);
  float* __restrict__ ob = out + ((size_t)bh << 20);
#pragma unroll
  for (int c = 0; c < 2; ++c) {
#pragma unroll
    for (int mr = 0; mr < 2; ++mr) {
      int mtile = 2 * c + mr;
#pragma unroll
      for (int nt = 0; nt < 4; nt++)
#pragma unroll
        for (int r = 0; r < 4; r++)
          wlds[(mr * 16 + quad * 4 + r) * LPAD + nt * 16 + l15] = acc[mtile][nt][r];
    }
    __asm__ volatile("s_waitcnt lgkmcnt(0)" ::: "memory");
#pragma unroll
    for (int g = 0; g < 8; ++g) {
      int row = g * 4 + quad;
      floatx4 v = *(const floatx4*)(wlds + row * LPAD + l15 * 4);
      __builtin_nontemporal_store(
          v, (floatx4*)(ob + (size_t)(row0 + c * 32 + row) * S_LEN + col0 + l15 * 4));
    }
    __asm__ volatile("s_waitcnt lgkmcnt(0)" ::: "memory");
  }
}

extern "C" void kernel_launch(void* const* d_in, const int* in_sizes, int n_in,
                              void* d_out, int out_size, void* d_ws, size_t ws_size,
                              hipStream_t stream) {
  const float* q  = (const float*)d_in[0];
  const float* k  = (const float*)d_in[1];
  const float* W  = (const float*)d_in[2];
  const float* b  = (const float*)d_in[3];
  const float* Wd = (const float*)d_in[4];
  float* out = (float*)d_out;

  unsigned short* qp = (unsigned short*)d_ws;                 // 8 MB
  unsigned short* kp = qp + (size_t)NBH * S_LEN * HD;         // 8 MB

  prep_all_kernel<<<5120, 256, 0, stream>>>(k, q, W, Wd, kp, qp);
  main_kernel<<<dim3(8, 8, NBH), 256, 0, stream>>>(qp, kp, b, Wd, out);
}